// Round 7
// baseline (101.329 us; speedup 1.0000x reference)
//
#include <hip/hip_runtime.h>

// MMD loss: source (4096,256) fp32, target (4096,256) fp32 -> scalar fp32.
// bandwidth closed form: sum(l2) = 2n*S - 2*||m||^2 (relu effect negligible).
// NO fences, NO atomics: visibility via kernel dispatch boundaries.
// Ledger: R1=99.2. R2: agent-scope atomics -> L2 wb/inv storm (-28).
//         R3: BK=32 dbuf -> barrier overhead (-2.7).
//         R4: launch_bounds(256,5) -> VGPR spills (-27).
//         R6: tiled+pre-swizzled tbT staging -> NEUTRAL (100.0) — L2 handles
//             scattered 64B segments fine; kept for simpler addressing.
// R7 change (single variable): PERSISTENT k_main — 1024 blocks (exactly
//   4/CU), each does 2-3 tiles. At tile boundaries the next tile's phase-0
//   stage is issued BEFORE the epilogue (T14 async-split); the epilogue's
//   wsum barrier doubles as the vmcnt drain. Removes 1056 cold phase-0
//   drains + hides 1056 epilogues. part[] slot mapping identical to the
//   old bid order -> k_final reduction bit-identical.
//   k_prep (256 blk): fp32->bf16 tbT (tiled layout), sq[], Spart/cpart
//   k_bw   (1 blk)  : reduce partials -> coef = log2(e)/(16*bw)
//   k_main (1024 blk): persistent 128x128 bf16 MFMA GEMM, BK=64 single-buf,
//                      XCD-chunked tile assignment, packed-f32 epilogue
//   k_final(1 blk)  : double-precision sum of part[] -> out

#define NROWS 8192
#define BHALF 4096
#define DDIM  256
#define TILE  128
#define NTILE 64
#define NBLK  2080   // NTILE*(NTILE+1)/2 = 8 * 260
#define NPER  1024   // persistent blocks (4/CU exactly)

typedef __attribute__((ext_vector_type(8))) short bf16x8;
typedef __attribute__((ext_vector_type(4))) float f32x4;
typedef __attribute__((ext_vector_type(2))) float f32x2;
typedef __attribute__((ext_vector_type(4))) unsigned short u16x4;

struct Ws {
  float coef;
  float Spart[256];
  float cpart[256][256];   // per-block column-sum partials
  float sq[NROWS];
  float part[NBLK];
};

__device__ __forceinline__ unsigned short f2bf(float x) {
  unsigned int u = __builtin_bit_cast(unsigned int, x);
  return (unsigned short)((u + 0x7fffu + ((u >> 16) & 1u)) >> 16);
}

__device__ __forceinline__ const float* row_ptr(const float* src, const float* tgt, int i) {
  return (i < BHALF) ? (src + (size_t)i * DDIM) : (tgt + (size_t)(i - BHALF) * DDIM);
}

__device__ __forceinline__ void derive_tile(int idx, int& ti_o, int& tj_o) {
  int t = (int)((129.0 - sqrt(129.0 * 129.0 - 8.0 * (double)idx)) * 0.5);
  while (64 * (t + 1) - ((t + 1) * t) / 2 <= idx) ++t;
  while (64 * t - (t * (t - 1)) / 2 > idx) --t;
  ti_o = t;
  tj_o = t + (idx - (64 * t - (t * (t - 1)) / 2));
}

// 256 blocks x 256 threads; 8 rows per wave. Partials only — no atomics.
// tbT write: row rg -> tile t=rg>>7, local row rl=rg&127. Lane covers 8 B =
// half of logical chunk cg=lane>>1; phase kc=cg>>3, chunk cwp=cg&7, stored
// at slot s=cwp^(rl&7).
__global__ __launch_bounds__(256) void k_prep(const float* __restrict__ src,
                                              const float* __restrict__ tgt,
                                              Ws* __restrict__ ws,
                                              unsigned short* __restrict__ tb,
                                              int conv) {
  __shared__ float cls[4][256];
  __shared__ float sred[4];
  int tid = threadIdx.x, wave = tid >> 6, lane = tid & 63;
  int row0 = blockIdx.x * 32 + wave * 8;
  float c0 = 0.f, c1 = 0.f, c2 = 0.f, c3 = 0.f;
  float s[8];
  #pragma unroll
  for (int r = 0; r < 8; ++r) {
    const float4* rp = (const float4*)row_ptr(src, tgt, row0 + r);
    float4 x = rp[lane];
    if (conv) {
      u16x4 b = { f2bf(x.x), f2bf(x.y), f2bf(x.z), f2bf(x.w) };
      int rg = row0 + r;
      int t = rg >> 7, rl = rg & 127;
      int cg = lane >> 1;
      int kc = cg >> 3, cwp = cg & 7;
      int slot = cwp ^ (rl & 7);
      *(u16x4*)&tb[((size_t)(t * 4 + kc) * 128 + rl) * 64 + slot * 8 + (lane & 1) * 4] = b;
    }
    c0 += x.x; c1 += x.y; c2 += x.z; c3 += x.w;
    s[r] = x.x * x.x + x.y * x.y + x.z * x.z + x.w * x.w;
  }
  #pragma unroll
  for (int off = 32; off > 0; off >>= 1) {
    #pragma unroll
    for (int r = 0; r < 8; ++r) s[r] += __shfl_xor(s[r], off);
  }
  if (lane == 0) {
    float Sw = 0.f;
    #pragma unroll
    for (int r = 0; r < 8; ++r) { ws->sq[row0 + r] = s[r]; Sw += s[r]; }
    sred[wave] = Sw;
  }
  cls[wave][lane * 4 + 0] = c0;
  cls[wave][lane * 4 + 1] = c1;
  cls[wave][lane * 4 + 2] = c2;
  cls[wave][lane * 4 + 3] = c3;
  __syncthreads();
  ws->cpart[blockIdx.x][tid] = cls[0][tid] + cls[1][tid] + cls[2][tid] + cls[3][tid];
  if (tid == 0) ws->Spart[blockIdx.x] = sred[0] + sred[1] + sred[2] + sred[3];
}

// 1 block x 256 threads: partials -> coef. Accumulation ORDER identical to
// the original serial loop -> coef bit-identical.
__global__ __launch_bounds__(256) void k_bw(Ws* __restrict__ ws) {
  __shared__ float redm[4], reds[4];
  int tid = threadIdx.x, wave = tid >> 6, lane = tid & 63;
  float mc = 0.f;
  for (int b0 = 0; b0 < 256; b0 += 16) {
    float v[16];
    #pragma unroll
    for (int j = 0; j < 16; ++j) v[j] = ws->cpart[b0 + j][tid];
    #pragma unroll
    for (int j = 0; j < 16; ++j) mc += v[j];
  }
  float p = mc * mc;
  float sp = ws->Spart[tid];
  #pragma unroll
  for (int off = 32; off > 0; off >>= 1) {
    p  += __shfl_xor(p, off);
    sp += __shfl_xor(sp, off);
  }
  if (lane == 0) { redm[wave] = p; reds[wave] = sp; }
  __syncthreads();
  if (tid == 0) {
    float msq = redm[0] + redm[1] + redm[2] + redm[3];
    float S   = reds[0] + reds[1] + reds[2] + reds[3];
    double n = (double)NROWS;
    double sum_l2 = 2.0 * n * (double)S - 2.0 * (double)msq;
    double bw = sum_l2 / (n * n - n) / 4.0;      // / KERNEL_MUL^(KERNEL_NUM/2)
    ws->coef = (float)(1.4426950408889634 / (16.0 * bw)); // log2(e)/(16*bw)
  }
}

// Stage one BK=64 phase from the TILED layout: per wave 4 x 1KB contiguous.
__device__ __forceinline__ void stage_tiles(const unsigned short* gA,
                                            const unsigned short* gB,
                                            unsigned short* lA, unsigned short* lB,
                                            int kc) {
  #pragma unroll
  for (int t = 0; t < 4; ++t) {
    __builtin_amdgcn_global_load_lds(
        (const __attribute__((address_space(1))) void*)(gA + (size_t)kc * 8192 + t * 512),
        (__attribute__((address_space(3))) void*)(lA + t * 512), 16, 0, 0);
    __builtin_amdgcn_global_load_lds(
        (const __attribute__((address_space(1))) void*)(gB + (size_t)kc * 8192 + t * 512),
        (__attribute__((address_space(3))) void*)(lB + t * 512), 16, 0, 0);
  }
}

// Persistent: 1024 blocks, 4 waves each. Block b = (XCD chunk c=b&7,
// slot p=b>>3); tile list idx = c*260 + p + w*128, w < (p<4 ? 3 : 2).
// part slot = (idx%260)*8 + idx/260 == the old blockIdx -> k_final order
// bit-identical.
template <int FAST>
__global__ __launch_bounds__(256, 4) void k_main(const unsigned short* __restrict__ tb,
                                                 const float* __restrict__ src,
                                                 const float* __restrict__ tgt,
                                                 Ws* __restrict__ ws) {
  int b = blockIdx.x;
  int c = b & 7, p = b >> 3;
  int nw = (p < 4) ? 3 : 2;
  int idx = c * 260 + p;

  __shared__ __align__(16) unsigned short As[TILE * 64];
  __shared__ __align__(16) unsigned short Bs[TILE * 64];
  __shared__ float wsum[4];

  int tid = threadIdx.x;
  int wave = tid >> 6, lane = tid & 63;
  int wm = wave >> 1, wn = wave & 1;           // 2x2 wave grid, 64x64 each
  int lr = lane & 15, q = lane >> 4;

  int ti, tj;
  derive_tile(idx, ti, tj);

  unsigned short* lA = &As[(wave * 32) * 64];
  unsigned short* lB = &Bs[(wave * 32) * 64];
  const unsigned short* gA = nullptr; const unsigned short* gB = nullptr;
  if (FAST) {
    gA = tb + (size_t)ti * 32768 + wave * 2048 + lane * 8;
    gB = tb + (size_t)tj * 32768 + wave * 2048 + lane * 8;
    stage_tiles(gA, gB, lA, lB, 0);            // prologue stage tile0/phase0
  }
  int r0 = tid >> 4, c4 = tid & 15;            // slow-path coords
  float coef = ws->coef;
  float coef2 = 2.f * coef;
  const f32x2 c2v = { coef2, coef2 };
  const int coffbase = 0;
  (void)coffbase;

  for (int w = 0; w < nw; ++w) {
    f32x4 zero = {0.f, 0.f, 0.f, 0.f};
    f32x4 acc[4][4];
    #pragma unroll
    for (int m = 0; m < 4; ++m)
      #pragma unroll
      for (int n = 0; n < 4; ++n) acc[m][n] = zero;

    if (FAST) {
      if (w == 0) __syncthreads();             // drain prologue stage
      #pragma unroll
      for (int kc = 0; kc < 4; ++kc) {
        if (kc) {
          __syncthreads();                     // prior compute reads done
          stage_tiles(gA, gB, lA, lB, kc);
          __syncthreads();                     // staged phase ready (vmcnt drain)
        }
        #pragma unroll
        for (int kk = 0; kk < 2; ++kk) {
          int cidx = ((kk * 4 + q) ^ (lr & 7)) << 3;
          bf16x8 af[4], bfr[4];
          #pragma unroll
          for (int m = 0; m < 4; ++m)
            af[m] = *(const bf16x8*)&As[(wm * 64 + m * 16 + lr) * 64 + cidx];
          #pragma unroll
          for (int n = 0; n < 4; ++n)
            bfr[n] = *(const bf16x8*)&Bs[(wn * 64 + n * 16 + lr) * 64 + cidx];
          #pragma unroll
          for (int m = 0; m < 4; ++m)
            #pragma unroll
            for (int n = 0; n < 4; ++n)
              acc[m][n] = __builtin_amdgcn_mfma_f32_16x16x32_bf16(af[m], bfr[n], acc[m][n], 0, 0, 0);
        }
      }
      __syncthreads();                         // all LDS reads of this tile done
    } else {
      int Ib = ti * TILE, Jb = tj * TILE;
      #pragma unroll
      for (int kc = 0; kc < 4; ++kc) {
        if (kc || w) __syncthreads();
        #pragma unroll
        for (int rr = 0; rr < 8; ++rr) {
          int row = rr * 16 + r0;
          int sw = ((c4 >> 1) ^ (row & 7)) * 8 + (c4 & 1) * 4;
          float4 va = ((const float4*)row_ptr(src, tgt, Ib + row))[kc * 16 + c4];
          u16x4 ba = { f2bf(va.x), f2bf(va.y), f2bf(va.z), f2bf(va.w) };
          *(u16x4*)&As[row * 64 + sw] = ba;
          float4 vb = ((const float4*)row_ptr(src, tgt, Jb + row))[kc * 16 + c4];
          u16x4 bb = { f2bf(vb.x), f2bf(vb.y), f2bf(vb.z), f2bf(vb.w) };
          *(u16x4*)&Bs[row * 64 + sw] = bb;
        }
        __syncthreads();
        #pragma unroll
        for (int kk = 0; kk < 2; ++kk) {
          int cidx = ((kk * 4 + q) ^ (lr & 7)) << 3;
          bf16x8 af[4], bfr[4];
          #pragma unroll
          for (int m = 0; m < 4; ++m)
            af[m] = *(const bf16x8*)&As[(wm * 64 + m * 16 + lr) * 64 + cidx];
          #pragma unroll
          for (int n = 0; n < 4; ++n)
            bfr[n] = *(const bf16x8*)&Bs[(wn * 64 + n * 16 + lr) * 64 + cidx];
          #pragma unroll
          for (int m = 0; m < 4; ++m)
            #pragma unroll
            for (int n = 0; n < 4; ++n)
              acc[m][n] = __builtin_amdgcn_mfma_f32_16x16x32_bf16(af[m], bfr[n], acc[m][n], 0, 0, 0);
        }
      }
    }

    // Save current tile identity for the epilogue, then issue the NEXT
    // tile's phase-0 stage (FAST): its latency hides under the epilogue,
    // and the wsum barrier below doubles as its vmcnt drain.
    int eti = ti, etj = tj, eidx = idx;
    bool more = (w + 1 < nw);
    if (more) {
      idx += 128;
      derive_tile(idx, ti, tj);
      if (FAST) {
        gA = tb + (size_t)ti * 32768 + wave * 2048 + lane * 8;
        gB = tb + (size_t)tj * 32768 + wave * 2048 + lane * 8;
        stage_tiles(gA, gB, lA, lB, 0);
      }
    }

    // Epilogue: arg = 2g*coef - (sqi+sqj)*coef; K = t+t^2+t^4+t^8+t^16.
    int ibase = eti * TILE + wm * 64;
    int jbase = etj * TILE + wn * 64;
    float nscj[4];
    f32x2 nsci01[4], nsci23[4];
    #pragma unroll
    for (int n = 0; n < 4; ++n) nscj[n] = -ws->sq[jbase + n * 16 + lr] * coef;
    #pragma unroll
    for (int m = 0; m < 4; ++m) {
      nsci01[m] = f32x2{ -ws->sq[ibase + m * 16 + q * 4 + 0] * coef,
                         -ws->sq[ibase + m * 16 + q * 4 + 1] * coef };
      nsci23[m] = f32x2{ -ws->sq[ibase + m * 16 + q * 4 + 2] * coef,
                         -ws->sq[ibase + m * 16 + q * 4 + 3] * coef };
    }
    f32x2 accA = {0.f, 0.f}, accB = {0.f, 0.f};
    f32x2 accC = {0.f, 0.f}, accD = {0.f, 0.f};
    #pragma unroll
    for (int m = 0; m < 4; ++m) {
      #pragma unroll
      for (int n = 0; n < 4; ++n) {
        f32x4 g = acc[m][n];
        f32x2 bj = { nscj[n], nscj[n] };
        f32x2 b01 = nsci01[m] + bj;
        f32x2 b23 = nsci23[m] + bj;
        f32x2 a01 = f32x2{g[0], g[1]} * c2v + b01;
        f32x2 a23 = f32x2{g[2], g[3]} * c2v + b23;
        f32x2 t0, t1;
        t0.x = __builtin_amdgcn_exp2f(a01.x); t0.y = __builtin_amdgcn_exp2f(a01.y);
        t1.x = __builtin_amdgcn_exp2f(a23.x); t1.y = __builtin_amdgcn_exp2f(a23.y);
        f32x2 p0 = t0 * t0, p1 = t1 * t1;
        f32x2 q0 = p0 * p0, q1 = p1 * p1;
        f32x2 r0v = q0 * q0, r1v = q1 * q1;
        accA += t0 + p0;
        accB += q0 + r0v;
        accA = r0v * r0v + accA;               // + t^16
        accC += t1 + p1;
        accD += q1 + r1v;
        accC = r1v * r1v + accC;
      }
    }
    float lsum = (accA.x + accA.y) + (accB.x + accB.y)
               + (accC.x + accC.y) + (accD.x + accD.y);
    #pragma unroll
    for (int off = 32; off > 0; off >>= 1) lsum += __shfl_xor(lsum, off);
    if (lane == 0) wsum[wave] = lsum;
    __syncthreads();                           // wsum ready + drains boundary stage
    if (tid == 0) {
      float tot = wsum[0] + wsum[1] + wsum[2] + wsum[3];
      float sA = (eti < 32) ? 1.f : -1.f;      // B=4096 = 32 tiles of 128
      float sB = (etj < 32) ? 1.f : -1.f;
      float fac = sA * sB * ((eti == etj) ? 1.f : 2.f);
      int slot = (eidx % 260) * 8 + eidx / 260;  // == old blockIdx mapping
      ws->part[slot] = fac * tot;              // plain store — NO fence/atomic
    }
  }
}

// 1 block x 256 threads: double-precision reduce of part[] -> out scalar.
__global__ __launch_bounds__(256) void k_final(const Ws* __restrict__ ws,
                                               float* __restrict__ out) {
  __shared__ double red[4];
  int tid = threadIdx.x, wave = tid >> 6, lane = tid & 63;
  double s = 0.0;
  for (int i = tid; i < NBLK; i += 256) s += (double)ws->part[i];
  #pragma unroll
  for (int off = 32; off > 0; off >>= 1) s += __shfl_xor(s, off);
  if (lane == 0) red[wave] = s;
  __syncthreads();
  if (tid == 0)
    out[0] = (float)((red[0] + red[1] + red[2] + red[3]) /
                     ((double)BHALF * (double)BHALF));
}

extern "C" void kernel_launch(void* const* d_in, const int* in_sizes, int n_in,
                              void* d_out, int out_size, void* d_ws, size_t ws_size,
                              hipStream_t stream) {
  const float* src = (const float*)d_in[0];
  const float* tgt = (const float*)d_in[1];
  Ws* ws = (Ws*)d_ws;
  float* out = (float*)d_out;

  size_t wsoff = (sizeof(Ws) + 255) & ~(size_t)255;
  size_t need = wsoff + (size_t)NROWS * DDIM * 2;
  bool fast = ws_size >= need;
  unsigned short* tb = fast ? (unsigned short*)((char*)d_ws + wsoff) : nullptr;

  hipLaunchKernelGGL(k_prep, dim3(256), dim3(256), 0, stream, src, tgt, ws, tb,
                     fast ? 1 : 0);
  hipLaunchKernelGGL(k_bw, dim3(1), dim3(256), 0, stream, ws);
  if (fast)
    hipLaunchKernelGGL((k_main<1>), dim3(NPER), dim3(256), 0, stream, tb, src, tgt, ws);
  else
    hipLaunchKernelGGL((k_main<0>), dim3(NPER), dim3(256), 0, stream, tb, src, tgt, ws);
  hipLaunchKernelGGL(k_final, dim3(1), dim3(256), 0, stream, ws, out);
}